// Round 17
// baseline (255.992 us; speedup 1.0000x reference)
//
#include <hip/hip_runtime.h>
#include <hip/hip_bf16.h>
#include <stdint.h>

typedef __bf16 bf16_t;
typedef bf16_t bf16x2 __attribute__((ext_vector_type(2)));
typedef bf16_t bf16x8 __attribute__((ext_vector_type(8)));
typedef float  f32x4  __attribute__((ext_vector_type(4)));
typedef float  f32x16 __attribute__((ext_vector_type(16)));
typedef unsigned uint2v __attribute__((ext_vector_type(2)));

#define NB_HEAD 16
#define DH      64
#define EMB     1024
#define BATCH   4
#define SEQ     2048
#define NTOK    (BATCH*SEQ)   // 8192

// scale * log2(e): folded into Q at projection time
#define QSCALE 0.1803368801111204f

// ---------------------------------------------------------------------------
// helpers
// ---------------------------------------------------------------------------
__device__ __forceinline__ void gload_lds16(const void* g, void* l) {
  __builtin_amdgcn_global_load_lds(
      (const __attribute__((address_space(1))) void*)g,
      (__attribute__((address_space(3))) void*)l, 16, 0, 0);
}

__device__ __forceinline__ uint32_t pkbf(float a, float b) {
  bf16x2 v = { (bf16_t)a, (bf16_t)b };     // fusable to v_cvt_pk_bf16_f32
  return __builtin_bit_cast(uint32_t, v);
}

__device__ __forceinline__ void cvt8_body(const float* __restrict__ in,
                                          bf16_t* __restrict__ out, int i) {
  const float4* p = reinterpret_cast<const float4*>(in) + (size_t)i * 2;
  float4 a = p[0], b = p[1];
  uint4 r;
  r.x = pkbf(a.x, a.y); r.y = pkbf(a.z, a.w);
  r.z = pkbf(b.x, b.y); r.w = pkbf(b.z, b.w);
  reinterpret_cast<uint4*>(out)[i] = r;
}

__device__ __forceinline__ void mkand_body(const uint8_t* __restrict__ m,
                                           uint16_t* __restrict__ out, int i) {
  uint2 v = reinterpret_cast<const uint2*>(m)[i];
  uint4 r;
  uint32_t lo = v.x, hi = v.y;
  uint16_t e[8];
#pragma unroll
  for (int j = 0; j < 4; j++) e[j]     = (uint16_t)(((lo >> (8 * j)) & 0xFF) - 1);
#pragma unroll
  for (int j = 0; j < 4; j++) e[4 + j] = (uint16_t)(((hi >> (8 * j)) & 0xFF) - 1);
  r.x = (uint32_t)e[0] | ((uint32_t)e[1] << 16);
  r.y = (uint32_t)e[2] | ((uint32_t)e[3] << 16);
  r.z = (uint32_t)e[4] | ((uint32_t)e[5] << 16);
  r.w = (uint32_t)e[6] | ((uint32_t)e[7] << 16);
  reinterpret_cast<uint4*>(out)[i] = r;
}

// ---------------------------------------------------------------------------
// prep: f32->bf16 conversions; mask expansion included only when MAND fits
// in its own region (blocks >= 14336). At HBM BW ceiling.
// ---------------------------------------------------------------------------
__global__ void __launch_bounds__(256)
prep(const float* __restrict__ hq, const float* __restrict__ hk,
     const float* __restrict__ hv, const float* __restrict__ Wq,
     const float* __restrict__ Wk, const float* __restrict__ Wv,
     const float* __restrict__ Wo,
     bf16_t* hq_b, bf16_t* hk_b, bf16_t* hv_b,
     bf16_t* Wq_b, bf16_t* Wk_b, bf16_t* Wv_b, bf16_t* Wo_b,
     const uint8_t* __restrict__ mask, uint16_t* __restrict__ mand) {
  const int bid = blockIdx.x;
  if (bid < 12288) {
    const int seg = bid >> 12;               // /4096
    const float* src = seg == 0 ? hq : seg == 1 ? hk : hv;
    bf16_t*      dst = seg == 0 ? hq_b : seg == 1 ? hk_b : hv_b;
    cvt8_body(src, dst, (bid & 4095) * 256 + (int)threadIdx.x);
  } else if (bid < 14336) {
    const int sb = bid - 12288;
    const int seg = sb >> 9;                 // /512
    const float* src = seg == 0 ? Wq : seg == 1 ? Wk : seg == 2 ? Wv : Wo;
    bf16_t*      dst = seg == 0 ? Wq_b : seg == 1 ? Wk_b : seg == 2 ? Wv_b : Wo_b;
    cvt8_body(src, dst, (sb & 511) * 256 + (int)threadIdx.x);
  } else {
    mkand_body(mask, mand, (bid - 14336) * 256 + (int)threadIdx.x);
  }
}

__global__ void __launch_bounds__(256)
mkand(const uint8_t* __restrict__ m, uint16_t* __restrict__ out) {
  mkand_body(m, out, blockIdx.x * 256 + (int)threadIdx.x);
}

// ---------------------------------------------------------------------------
// GEMMs: R15-exact config (128x128 tile, BK=32, 2-phase dbuf, XCD swizzle).
// BN=64 variant (R16) regressed -13% — reverted.
// ---------------------------------------------------------------------------
#define BM 128
#define BN 128
#define BKT 32

// Fused QKV GEMM: grid (8,64,3).
__global__ void __launch_bounds__(256, 4)
gemm_qkv3(const bf16_t* __restrict__ hq_b, const bf16_t* __restrict__ hk_b,
          const bf16_t* __restrict__ hv_b,
          const bf16_t* __restrict__ Wq_b, const bf16_t* __restrict__ Wk_b,
          const bf16_t* __restrict__ Wv_b,
          bf16_t* __restrict__ Qb, bf16_t* __restrict__ Kf,
          bf16_t* __restrict__ Vf) {
  __shared__ bf16_t As[2][BM * BKT];
  __shared__ bf16_t Bs[2][BN * BKT];
  const int K = EMB;
  const int z = blockIdx.z;
  const bf16_t* A  = z == 0 ? hq_b : z == 1 ? hk_b : hv_b;
  const bf16_t* Bw = z == 0 ? Wq_b : z == 1 ? Wk_b : Wv_b;

  const int t    = threadIdx.x;
  const int lane = t & 63, w = t >> 6;
  const int wr = w >> 1, wc = w & 1;
  const int l15 = lane & 15, l4 = lane >> 4;

  const int lin = blockIdx.x + 8 * blockIdx.y;
  const int nl  = (lin & 7) * 64 + (lin >> 3);
  const int rowBase = (nl >> 3) * BM, colBase = (nl & 7) * BN;

  f32x4 acc[4][4];
#pragma unroll
  for (int i = 0; i < 4; i++)
#pragma unroll
    for (int j = 0; j < 4; j++) acc[i][j] = f32x4{0.f, 0.f, 0.f, 0.f};

  const int t16 = t * 16;

#pragma unroll
  for (int i = 0; i < 2; ++i) {
    int off  = i * 4096 + t16;
    int row  = off >> 6, colb = off & 63;
    gload_lds16((const char*)A  + (((size_t)(rowBase + row)) * K) * 2 + colb, (char*)As[0] + off);
    gload_lds16((const char*)Bw + (((size_t)(colBase + row)) * K) * 2 + colb, (char*)Bs[0] + off);
  }
  __syncthreads();

  int cur = 0;
  for (int k0 = 0; k0 < K; k0 += BKT) {
    if (k0 + BKT < K) {
      const int nb = cur ^ 1;
#pragma unroll
      for (int i = 0; i < 2; ++i) {
        int off  = i * 4096 + t16;
        int row  = off >> 6, colb = off & 63;
        gload_lds16((const char*)A  + (((size_t)(rowBase + row)) * K + k0 + BKT) * 2 + colb, (char*)As[nb] + off);
        gload_lds16((const char*)Bw + (((size_t)(colBase + row)) * K + k0 + BKT) * 2 + colb, (char*)Bs[nb] + off);
      }
    }
    {
      bf16x8 af[4], bfb[4];
#pragma unroll
      for (int mi = 0; mi < 4; mi++)
        af[mi] = *reinterpret_cast<const bf16x8*>(
            &As[cur][(wr * 64 + mi * 16 + l15) * BKT + l4 * 8]);
#pragma unroll
      for (int ni = 0; ni < 4; ni++)
        bfb[ni] = *reinterpret_cast<const bf16x8*>(
            &Bs[cur][(wc * 64 + ni * 16 + l15) * BKT + l4 * 8]);
      __builtin_amdgcn_s_setprio(1);
#pragma unroll
      for (int mi = 0; mi < 4; mi++)
#pragma unroll
        for (int ni = 0; ni < 4; ni++)
          acc[mi][ni] = __builtin_amdgcn_mfma_f32_16x16x32_bf16(
              af[mi], bfb[ni], acc[mi][ni], 0, 0, 0);
      __builtin_amdgcn_s_setprio(0);
    }
    __syncthreads();
    cur ^= 1;
  }

#pragma unroll
  for (int mi = 0; mi < 4; mi++) {
#pragma unroll
    for (int ni = 0; ni < 4; ni++) {
      const int m0 = rowBase + wr * 64 + mi * 16 + l4 * 4;
      const int n  = colBase + wc * 64 + ni * 16 + l15;
      if (z == 0) {
#pragma unroll
        for (int r = 0; r < 4; r++)
          Qb[(size_t)(m0 + r) * EMB + n] = (bf16_t)(acc[mi][ni][r] * QSCALE);
      } else if (z == 1) {
        // K fragment layout
#pragma unroll
        for (int r = 0; r < 4; r++) {
          int m = m0 + r;
          const int bq = m >> 11, s = m & 2047, hh = n >> 6, d = n & 63;
          size_t local = (size_t)(s >> 6) * 4096 + ((s >> 5) & 1) * 2048 +
                         (d >> 4) * 512 + ((d >> 3) & 1) * 256 + (s & 31) * 8 + (d & 7);
          Kf[(size_t)(bq * 16 + hh) * 131072 + local] = (bf16_t)acc[mi][ni][r];
        }
      } else {
        // V fragment layout: s0..s0+3 consecutive -> one 8B store
        const int bq = m0 >> 11, s0 = m0 & 2047, hh = n >> 6, d = n & 63;
        size_t local = (size_t)(s0 >> 6) * 4096 + ((s0 >> 4) & 3) * 1024 +
                       (d >> 5) * 512 + ((s0 >> 3) & 1) * 256 + (d & 31) * 8 + (s0 & 7);
        uint2 st;
        st.x = pkbf(acc[mi][ni][0], acc[mi][ni][1]);
        st.y = pkbf(acc[mi][ni][2], acc[mi][ni][3]);
        *reinterpret_cast<uint2*>(Vf + (size_t)(bq * 16 + hh) * 131072 + local) = st;
      }
    }
  }
}

// Output-projection GEMM: f32 C + residual.
__global__ void __launch_bounds__(256, 4)
gemm_out(const bf16_t* __restrict__ A, const bf16_t* __restrict__ Bw,
         float* __restrict__ Cf, const float* __restrict__ resid) {
  __shared__ bf16_t As[2][BM * BKT];
  __shared__ bf16_t Bs[2][BN * BKT];
  const int K = EMB, N = EMB;
  const int t    = threadIdx.x;
  const int lane = t & 63, w = t >> 6;
  const int wr = w >> 1, wc = w & 1;
  const int l15 = lane & 15, l4 = lane >> 4;

  const int lin = blockIdx.x + 8 * blockIdx.y;
  const int nl  = (lin & 7) * 64 + (lin >> 3);
  const int rowBase = (nl >> 3) * BM, colBase = (nl & 7) * BN;

  f32x4 acc[4][4];
#pragma unroll
  for (int i = 0; i < 4; i++)
#pragma unroll
    for (int j = 0; j < 4; j++) acc[i][j] = f32x4{0.f, 0.f, 0.f, 0.f};

  const int t16 = t * 16;

#pragma unroll
  for (int i = 0; i < 2; ++i) {
    int off  = i * 4096 + t16;
    int row  = off >> 6, colb = off & 63;
    gload_lds16((const char*)A  + (((size_t)(rowBase + row)) * K) * 2 + colb, (char*)As[0] + off);
    gload_lds16((const char*)Bw + (((size_t)(colBase + row)) * K) * 2 + colb, (char*)Bs[0] + off);
  }
  __syncthreads();

  int cur = 0;
  for (int k0 = 0; k0 < K; k0 += BKT) {
    if (k0 + BKT < K) {
      const int nb = cur ^ 1;
#pragma unroll
      for (int i = 0; i < 2; ++i) {
        int off  = i * 4096 + t16;
        int row  = off >> 6, colb = off & 63;
        gload_lds16((const char*)A  + (((size_t)(rowBase + row)) * K + k0 + BKT) * 2 + colb, (char*)As[nb] + off);
        gload_lds16((const char*)Bw + (((size_t)(colBase + row)) * K + k0 + BKT) * 2 + colb, (char*)Bs[nb] + off);
      }
    }
    {
      bf16x8 af[4], bfb[4];
#pragma unroll
      for (int mi = 0; mi < 4; mi++)
        af[mi] = *reinterpret_cast<const bf16x8*>(
            &As[cur][(wr * 64 + mi * 16 + l15) * BKT + l4 * 8]);
#pragma unroll
      for (int ni = 0; ni < 4; ni++)
        bfb[ni] = *reinterpret_cast<const bf16x8*>(
            &Bs[cur][(wc * 64 + ni * 16 + l15) * BKT + l4 * 8]);
      __builtin_amdgcn_s_setprio(1);
#pragma unroll
      for (int mi = 0; mi < 4; mi++)
#pragma unroll
        for (int ni = 0; ni < 4; ni++)
          acc[mi][ni] = __builtin_amdgcn_mfma_f32_16x16x32_bf16(
              af[mi], bfb[ni], acc[mi][ni], 0, 0, 0);
      __builtin_amdgcn_s_setprio(0);
    }
    __syncthreads();
    cur ^= 1;
  }

#pragma unroll
  for (int mi = 0; mi < 4; mi++) {
#pragma unroll
    for (int ni = 0; ni < 4; ni++) {
      const int m0 = rowBase + wr * 64 + mi * 16 + l4 * 4;
      const int n  = colBase + wc * 64 + ni * 16 + l15;
#pragma unroll
      for (int r = 0; r < 4; r++) {
        int m = m0 + r;
        Cf[(size_t)m * N + n] = acc[mi][ni][r] + resid[(size_t)m * N + n];
      }
    }
  }
}

// ---------------------------------------------------------------------------
// Flash attention — R10/R15 inner loop VERBATIM (proven: VGPR 56, no scratch,
// 0 bank conflicts). SPLIT=1: each block sweeps HALF the KV range (grid 2x
// -> 32 waves/CU vs 16; attn was grid-bound) and writes raw f32 partials —
// O = O0+O1, l = l0+l1 combine exactly (no online max => pure addition).
// SPLIT=0: original full-sweep, normalize + bf16 ctx store.
// ---------------------------------------------------------------------------
template<int SPLIT>
__global__ void __launch_bounds__(512, 2)
attn32(const bf16_t* __restrict__ Qb, const bf16_t* __restrict__ Kh,
       const bf16_t* __restrict__ Vt, const uint16_t* __restrict__ Mand,
       bf16_t* __restrict__ ctx, float* __restrict__ O0, float* __restrict__ O1,
       float* __restrict__ L0, float* __restrict__ L1) {
  __shared__ __align__(16) bf16_t Ks[2][64 * 64];
  __shared__ __align__(16) bf16_t Vs[2][64 * 64];

  const int t = threadIdx.x, lane = t & 63, wid = t >> 6;
  const int q = lane & 31, hi = lane >> 5;
  const int l16 = lane * 16;

  // XCD swizzle; sharers of one (b,h[,half]) K/V set land on the same XCD
  const int lin = blockIdx.x + (SPLIT ? 16 : 8) * (blockIdx.y + 16 * blockIdx.z);
  const int nl  = (lin & 7) * (SPLIT ? 128 : 64) + (lin >> 3);
  int half, bx, h, b;
  if (SPLIT) { half = nl & 1; bx = (nl >> 1) & 7; h = (nl >> 4) & 15; b = nl >> 8; }
  else       { half = 0;      bx = nl & 7;        h = (nl >> 3) & 15; b = nl >> 7; }

  const int q0 = bx * 256 + wid * 32;
  const int qrow = b * SEQ + q0 + q;
  const int NT = SPLIT ? 16 : 32;   // 64-k tiles this block sweeps

  const char* kg = (const char*)(Kh + ((size_t)(b * NB_HEAD + h)) * SEQ * DH)
                   + (size_t)half * 16 * 8192;
  const char* vg = (const char*)(Vt + ((size_t)(b * NB_HEAD + h)) * SEQ * DH)
                   + (size_t)half * 16 * 8192;

  const bf16_t* qp = Qb + (size_t)qrow * EMB + h * DH + hi * 8;
  bf16x8 qf[4];
#pragma unroll
  for (int d = 0; d < 4; d++) qf[d] = *reinterpret_cast<const bf16x8*>(qp + d * 16);

  f32x16 o0 = {0}, o1 = {0};
  float lrun = 0.f;
  const uint16_t* mbase = Mand + (size_t)qrow * SEQ + half * (SEQ / 2) * SPLIT;

  // prologue: stage tile 0 into buf 0 (linear 8KB copies)
  gload_lds16(kg + t * 16, (char*)Ks[0] + t * 16);
  gload_lds16(vg + t * 16, (char*)Vs[0] + t * 16);
  __syncthreads();

  int cur = 0;
  for (int tt = 0; tt < NT; ++tt) {
    if (tt + 1 < NT) {
      const int nb = cur ^ 1;
      gload_lds16(kg + (size_t)(tt + 1) * 8192 + t * 16, (char*)Ks[nb] + t * 16);
      gload_lds16(vg + (size_t)(tt + 1) * 8192 + t * 16, (char*)Vs[nb] + t * 16);
    }

    const char* kls = (const char*)Ks[cur];
    f32x16 p0 = {0}, p1 = {0};
    __builtin_amdgcn_s_setprio(1);
#pragma unroll
    for (int dsl = 0; dsl < 4; dsl++) {
      bf16x8 kf0 = *reinterpret_cast<const bf16x8*>(kls + dsl * 1024 + l16);
      bf16x8 kf1 = *reinterpret_cast<const bf16x8*>(kls + 4096 + dsl * 1024 + l16);
      p0 = __builtin_amdgcn_mfma_f32_32x32x16_bf16(kf0, qf[dsl], p0, 0, 0, 0);
      p1 = __builtin_amdgcn_mfma_f32_32x32x16_bf16(kf1, qf[dsl], p1, 0, 0, 0);
    }
    __builtin_amdgcn_s_setprio(0);

    uint4 mv[4];
#pragma unroll
    for (int ks = 0; ks < 4; ks++)
      mv[ks] = *reinterpret_cast<const uint4*>(mbase + tt * 64 + 16 * ks + 8 * hi);

    float ps = 0.f;
#pragma unroll
    for (int i = 0; i < 16; i++) { p0[i] = __builtin_amdgcn_exp2f(p0[i]); ps += p0[i]; }
#pragma unroll
    for (int i = 0; i < 16; i++) { p1[i] = __builtin_amdgcn_exp2f(p1[i]); ps += p1[i]; }
    ps += __shfl_xor(ps, 32);
    lrun += ps;

    const char* vls = (const char*)Vs[cur];
#pragma unroll
    for (int ks = 0; ks < 4; ks++) {
      const int s8 = (ks & 1) * 8;
      float e0, e1, e2, e3, e4, e5, e6, e7;
      if (ks < 2) {
        e0 = p0[s8+0]; e1 = p0[s8+1]; e2 = p0[s8+2]; e3 = p0[s8+3];
        e4 = p0[s8+4]; e5 = p0[s8+5]; e6 = p0[s8+6]; e7 = p0[s8+7];
      } else {
        e0 = p1[s8+0]; e1 = p1[s8+1]; e2 = p1[s8+2]; e3 = p1[s8+3];
        e4 = p1[s8+4]; e5 = p1[s8+5]; e6 = p1[s8+6]; e7 = p1[s8+7];
      }
      uint32_t a0 = pkbf(e0, e1), a1 = pkbf(e2, e3);
      uint32_t a2 = pkbf(e4, e5), a3 = pkbf(e6, e7);
      uint2v s02 = __builtin_amdgcn_permlane32_swap(a0, a2, false, false);
      uint2v s13 = __builtin_amdgcn_permlane32_swap(a1, a3, false, false);
      uint4 fr;
      fr.x = s02[0]; fr.y = s13[0]; fr.z = s02[1]; fr.w = s13[1];
      fr.x &= mv[ks].x; fr.y &= mv[ks].y; fr.z &= mv[ks].z; fr.w &= mv[ks].w;
      bf16x8 pa = __builtin_bit_cast(bf16x8, fr);
      bf16x8 vf0 = *reinterpret_cast<const bf16x8*>(vls + ks * 2048 + l16);
      bf16x8 vf1 = *reinterpret_cast<const bf16x8*>(vls + ks * 2048 + 1024 + l16);
      __builtin_amdgcn_s_setprio(1);
      o0 = __builtin_amdgcn_mfma_f32_32x32x16_bf16(vf0, pa, o0, 0, 0, 0);
      o1 = __builtin_amdgcn_mfma_f32_32x32x16_bf16(vf1, pa, o1, 0, 0, 0);
      __builtin_amdgcn_s_setprio(0);
    }

    __syncthreads();
    cur ^= 1;
  }

  if (SPLIT) {
    // raw f32 partials; combine kernel adds halves and normalizes
    float* op = (half ? O1 : O0) + (size_t)qrow * EMB + h * DH;
#pragma unroll
    for (int g = 0; g < 4; g++) {
      float4 s0 = { o0[4*g+0], o0[4*g+1], o0[4*g+2], o0[4*g+3] };
      float4 s1 = { o1[4*g+0], o1[4*g+1], o1[4*g+2], o1[4*g+3] };
      *reinterpret_cast<float4*>(op + 8 * g + 4 * hi) = s0;
      *reinterpret_cast<float4*>(op + 32 + 8 * g + 4 * hi) = s1;
    }
    if (hi == 0) (half ? L1 : L0)[qrow * NB_HEAD + h] = lrun;
  } else {
    float inv = 1.0f / lrun;
    bf16_t* cp = ctx + (size_t)qrow * EMB + h * DH;
#pragma unroll
    for (int g = 0; g < 4; g++) {
      uint2 st;
      st.x = pkbf(o0[4*g+0] * inv, o0[4*g+1] * inv);
      st.y = pkbf(o0[4*g+2] * inv, o0[4*g+3] * inv);
      *reinterpret_cast<uint2*>(cp + 8 * g + 4 * hi) = st;
      st.x = pkbf(o1[4*g+0] * inv, o1[4*g+1] * inv);
      st.y = pkbf(o1[4*g+2] * inv, o1[4*g+3] * inv);
      *reinterpret_cast<uint2*>(cp + 32 + 8 * g + 4 * hi) = st;
    }
  }
}

// ---------------------------------------------------------------------------
// reduce: ctx = (O0 + O1) / (l0 + l1), bf16. 8 elems/thread (same (q,h)).
// ---------------------------------------------------------------------------
__global__ void __launch_bounds__(256)
reduce_ctx(const float* __restrict__ O0, const float* __restrict__ O1,
           const float* __restrict__ L0, const float* __restrict__ L1,
           bf16_t* __restrict__ ctx) {
  const int i = blockIdx.x * 256 + (int)threadIdx.x;
  const size_t base = (size_t)i * 8;
  const int qh = (int)(base >> 6);
  const float inv = 1.0f / (L0[qh] + L1[qh]);
  float4 a0 = *reinterpret_cast<const float4*>(O0 + base);
  float4 a1 = *reinterpret_cast<const float4*>(O0 + base + 4);
  float4 b0 = *reinterpret_cast<const float4*>(O1 + base);
  float4 b1 = *reinterpret_cast<const float4*>(O1 + base + 4);
  uint4 r;
  r.x = pkbf((a0.x + b0.x) * inv, (a0.y + b0.y) * inv);
  r.y = pkbf((a0.z + b0.z) * inv, (a0.w + b0.w) * inv);
  r.z = pkbf((a1.x + b1.x) * inv, (a1.y + b1.y) * inv);
  r.w = pkbf((a1.z + b1.z) * inv, (a1.w + b1.w) * inv);
  reinterpret_cast<uint4*>(ctx)[i] = r;
}

// ---------------------------------------------------------------------------
// launcher
// ws (bigws, >=152Mi): [0,48) h*_b -> O1(32Mi)+L0/L1 after qkv3; [48,96) QKV;
// [96,112) ctx; [112,120) W; [120,152) Mand. O0 -> d_out (fully overwritten
// by gemm_out afterwards).
// ---------------------------------------------------------------------------
extern "C" void kernel_launch(void* const* d_in, const int* in_sizes, int n_in,
                              void* d_out, int out_size, void* d_ws, size_t ws_size,
                              hipStream_t stream) {
  const float*   hq   = (const float*)d_in[0];
  const float*   hk   = (const float*)d_in[1];
  const float*   hv   = (const float*)d_in[2];
  const uint8_t* mask = (const uint8_t*)d_in[3];
  const float*   Wq   = (const float*)d_in[4];
  const float*   Wk   = (const float*)d_in[5];
  const float*   Wv   = (const float*)d_in[6];
  const float*   Wo   = (const float*)d_in[7];
  float* out = (float*)d_out;

  char* ws = (char*)d_ws;
  const size_t SZ_H = (size_t)NTOK * EMB * 2;        // 16 MiB
  const size_t SZ_W = (size_t)EMB * EMB * 2;         // 2 MiB
  bf16_t* hq_b = (bf16_t*)(ws + 0 * SZ_H);
  bf16_t* hk_b = (bf16_t*)(ws + 1 * SZ_H);
  bf16_t* hv_b = (bf16_t*)(ws + 2 * SZ_H);
  bf16_t* Qb   = (bf16_t*)(ws + 3 * SZ_H);
  bf16_t* Kf   = (bf16_t*)(ws + 4 * SZ_H);
  bf16_t* Vf   = (bf16_t*)(ws + 5 * SZ_H);
  bf16_t* ctx  = (bf16_t*)(ws + 6 * SZ_H);
  bf16_t* Wq_b = (bf16_t*)(ws + 7 * SZ_H + 0 * SZ_W);
  bf16_t* Wk_b = (bf16_t*)(ws + 7 * SZ_H + 1 * SZ_W);
  bf16_t* Wv_b = (bf16_t*)(ws + 7 * SZ_H + 2 * SZ_W);
  bf16_t* Wo_b = (bf16_t*)(ws + 7 * SZ_H + 3 * SZ_W);

  const size_t MAND_OFF = 7 * SZ_H + 4 * SZ_W;                 // 120 MiB
  const size_t MAND_SZ  = (size_t)BATCH * SEQ * SEQ * 2;       // 32 MiB
  const bool bigws = ws_size >= MAND_OFF + MAND_SZ;
  uint16_t* Mand = bigws ? (uint16_t*)(ws + MAND_OFF) : (uint16_t*)ws;

  // KV-split partials (bigws path): O0 -> d_out; O1/L over dead h*_b region
  float* O0 = (float*)d_out;
  float* O1 = (float*)(ws + 0);                      // 32 MiB over hq_b/hk_b
  float* L0 = (float*)(ws + 2 * SZ_H);               // over hv_b
  float* L1 = (float*)(ws + 2 * SZ_H + 512 * 1024);

  prep<<<bigws ? 22528 : 14336, 256, 0, stream>>>(
      hq, hk, hv, Wq, Wk, Wv, Wo,
      hq_b, hk_b, hv_b, Wq_b, Wk_b, Wv_b, Wo_b, mask, Mand);

  gemm_qkv3<<<dim3(8, 64, 3), 256, 0, stream>>>(hq_b, hk_b, hv_b,
                                                Wq_b, Wk_b, Wv_b, Qb, Kf, Vf);

  if (!bigws) mkand<<<8192, 256, 0, stream>>>(mask, Mand);

  if (bigws) {
    attn32<1><<<dim3(16, NB_HEAD, BATCH), 512, 0, stream>>>(
        Qb, Kf, Vf, Mand, nullptr, O0, O1, L0, L1);
    reduce_ctx<<<NTOK * EMB / 8 / 256, 256, 0, stream>>>(O0, O1, L0, L1, ctx);
  } else {
    attn32<0><<<dim3(8, NB_HEAD, BATCH), 512, 0, stream>>>(
        Qb, Kf, Vf, Mand, ctx, nullptr, nullptr, nullptr, nullptr);
  }

  gemm_out<<<dim3(8, 64), 256, 0, stream>>>(ctx, Wo_b, out, hq);
}

// Round 18
// 229.637 us; speedup vs baseline: 1.1148x; 1.1148x over previous
//
#include <hip/hip_runtime.h>
#include <hip/hip_bf16.h>
#include <stdint.h>

typedef __bf16 bf16_t;
typedef bf16_t bf16x2 __attribute__((ext_vector_type(2)));
typedef bf16_t bf16x8 __attribute__((ext_vector_type(8)));
typedef float  f32x4  __attribute__((ext_vector_type(4)));
typedef float  f32x16 __attribute__((ext_vector_type(16)));
typedef unsigned uint2v __attribute__((ext_vector_type(2)));

#define NB_HEAD 16
#define DH      64
#define EMB     1024
#define BATCH   4
#define SEQ     2048
#define NTOK    (BATCH*SEQ)   // 8192

// scale * log2(e): folded into Q at projection time
#define QSCALE 0.1803368801111204f

// ---------------------------------------------------------------------------
// helpers
// ---------------------------------------------------------------------------
__device__ __forceinline__ void gload_lds16(const void* g, void* l) {
  __builtin_amdgcn_global_load_lds(
      (const __attribute__((address_space(1))) void*)g,
      (__attribute__((address_space(3))) void*)l, 16, 0, 0);
}

__device__ __forceinline__ uint32_t pkbf(float a, float b) {
  bf16x2 v = { (bf16_t)a, (bf16_t)b };     // fusable to v_cvt_pk_bf16_f32
  return __builtin_bit_cast(uint32_t, v);
}

__device__ __forceinline__ void cvt8_body(const float* __restrict__ in,
                                          bf16_t* __restrict__ out, int i) {
  const float4* p = reinterpret_cast<const float4*>(in) + (size_t)i * 2;
  float4 a = p[0], b = p[1];
  uint4 r;
  r.x = pkbf(a.x, a.y); r.y = pkbf(a.z, a.w);
  r.z = pkbf(b.x, b.y); r.w = pkbf(b.z, b.w);
  reinterpret_cast<uint4*>(out)[i] = r;
}

__device__ __forceinline__ void mkand_body(const uint8_t* __restrict__ m,
                                           uint16_t* __restrict__ out, int i) {
  uint2 v = reinterpret_cast<const uint2*>(m)[i];
  uint4 r;
  uint32_t lo = v.x, hi = v.y;
  uint16_t e[8];
#pragma unroll
  for (int j = 0; j < 4; j++) e[j]     = (uint16_t)(((lo >> (8 * j)) & 0xFF) - 1);
#pragma unroll
  for (int j = 0; j < 4; j++) e[4 + j] = (uint16_t)(((hi >> (8 * j)) & 0xFF) - 1);
  r.x = (uint32_t)e[0] | ((uint32_t)e[1] << 16);
  r.y = (uint32_t)e[2] | ((uint32_t)e[3] << 16);
  r.z = (uint32_t)e[4] | ((uint32_t)e[5] << 16);
  r.w = (uint32_t)e[6] | ((uint32_t)e[7] << 16);
  reinterpret_cast<uint4*>(out)[i] = r;
}

// ---------------------------------------------------------------------------
// prep: all f32->bf16 conversions (+ optional mask expansion) in ONE launch.
// At HBM BW ceiling (216 MB / ~34 us ≈ 6.3 TB/s) — do not touch.
// ---------------------------------------------------------------------------
__global__ void __launch_bounds__(256)
prep(const float* __restrict__ hq, const float* __restrict__ hk,
     const float* __restrict__ hv, const float* __restrict__ Wq,
     const float* __restrict__ Wk, const float* __restrict__ Wv,
     const float* __restrict__ Wo,
     bf16_t* hq_b, bf16_t* hk_b, bf16_t* hv_b,
     bf16_t* Wq_b, bf16_t* Wk_b, bf16_t* Wv_b, bf16_t* Wo_b,
     const uint8_t* __restrict__ mask, uint16_t* __restrict__ mand) {
  const int bid = blockIdx.x;
  if (bid < 12288) {
    const int seg = bid >> 12;               // /4096
    const float* src = seg == 0 ? hq : seg == 1 ? hk : hv;
    bf16_t*      dst = seg == 0 ? hq_b : seg == 1 ? hk_b : hv_b;
    cvt8_body(src, dst, (bid & 4095) * 256 + (int)threadIdx.x);
  } else if (bid < 14336) {
    const int sb = bid - 12288;
    const int seg = sb >> 9;                 // /512
    const float* src = seg == 0 ? Wq : seg == 1 ? Wk : seg == 2 ? Wv : Wo;
    bf16_t*      dst = seg == 0 ? Wq_b : seg == 1 ? Wk_b : seg == 2 ? Wv_b : Wo_b;
    cvt8_body(src, dst, (sb & 511) * 256 + (int)threadIdx.x);
  } else {
    mkand_body(mask, mand, (bid - 14336) * 256 + (int)threadIdx.x);
  }
}

__global__ void __launch_bounds__(256)
mkand(const uint8_t* __restrict__ m, uint16_t* __restrict__ out) {
  mkand_body(m, out, blockIdx.x * 256 + (int)threadIdx.x);
}

// ---------------------------------------------------------------------------
// GEMMs: best-known config (128x128 tile, BK=32, 2-phase dbuf, XCD swizzle).
// BN=64 (R16) and KV-split (R17) both regressed — this is the R15 state.
// ---------------------------------------------------------------------------
#define BM 128
#define BN 128
#define BKT 32

// Fused QKV GEMM: grid (8,64,3). z=0: Q row-major x QSCALE; z=1: K
// attn-fragment; z=2: V attn-fragment.
__global__ void __launch_bounds__(256, 4)
gemm_qkv3(const bf16_t* __restrict__ hq_b, const bf16_t* __restrict__ hk_b,
          const bf16_t* __restrict__ hv_b,
          const bf16_t* __restrict__ Wq_b, const bf16_t* __restrict__ Wk_b,
          const bf16_t* __restrict__ Wv_b,
          bf16_t* __restrict__ Qb, bf16_t* __restrict__ Kf,
          bf16_t* __restrict__ Vf) {
  __shared__ bf16_t As[2][BM * BKT];
  __shared__ bf16_t Bs[2][BN * BKT];
  const int K = EMB;
  const int z = blockIdx.z;
  const bf16_t* A  = z == 0 ? hq_b : z == 1 ? hk_b : hv_b;
  const bf16_t* Bw = z == 0 ? Wq_b : z == 1 ? Wk_b : Wv_b;

  const int t    = threadIdx.x;
  const int lane = t & 63, w = t >> 6;
  const int wr = w >> 1, wc = w & 1;
  const int l15 = lane & 15, l4 = lane >> 4;

  const int lin = blockIdx.x + 8 * blockIdx.y;
  const int nl  = (lin & 7) * 64 + (lin >> 3);
  const int rowBase = (nl >> 3) * BM, colBase = (nl & 7) * BN;

  f32x4 acc[4][4];
#pragma unroll
  for (int i = 0; i < 4; i++)
#pragma unroll
    for (int j = 0; j < 4; j++) acc[i][j] = f32x4{0.f, 0.f, 0.f, 0.f};

  const int t16 = t * 16;

#pragma unroll
  for (int i = 0; i < 2; ++i) {
    int off  = i * 4096 + t16;
    int row  = off >> 6, colb = off & 63;
    gload_lds16((const char*)A  + (((size_t)(rowBase + row)) * K) * 2 + colb, (char*)As[0] + off);
    gload_lds16((const char*)Bw + (((size_t)(colBase + row)) * K) * 2 + colb, (char*)Bs[0] + off);
  }
  __syncthreads();

  int cur = 0;
  for (int k0 = 0; k0 < K; k0 += BKT) {
    if (k0 + BKT < K) {
      const int nb = cur ^ 1;
#pragma unroll
      for (int i = 0; i < 2; ++i) {
        int off  = i * 4096 + t16;
        int row  = off >> 6, colb = off & 63;
        gload_lds16((const char*)A  + (((size_t)(rowBase + row)) * K + k0 + BKT) * 2 + colb, (char*)As[nb] + off);
        gload_lds16((const char*)Bw + (((size_t)(colBase + row)) * K + k0 + BKT) * 2 + colb, (char*)Bs[nb] + off);
      }
    }
    {
      bf16x8 af[4], bfb[4];
#pragma unroll
      for (int mi = 0; mi < 4; mi++)
        af[mi] = *reinterpret_cast<const bf16x8*>(
            &As[cur][(wr * 64 + mi * 16 + l15) * BKT + l4 * 8]);
#pragma unroll
      for (int ni = 0; ni < 4; ni++)
        bfb[ni] = *reinterpret_cast<const bf16x8*>(
            &Bs[cur][(wc * 64 + ni * 16 + l15) * BKT + l4 * 8]);
      __builtin_amdgcn_s_setprio(1);
#pragma unroll
      for (int mi = 0; mi < 4; mi++)
#pragma unroll
        for (int ni = 0; ni < 4; ni++)
          acc[mi][ni] = __builtin_amdgcn_mfma_f32_16x16x32_bf16(
              af[mi], bfb[ni], acc[mi][ni], 0, 0, 0);
      __builtin_amdgcn_s_setprio(0);
    }
    __syncthreads();
    cur ^= 1;
  }

#pragma unroll
  for (int mi = 0; mi < 4; mi++) {
#pragma unroll
    for (int ni = 0; ni < 4; ni++) {
      const int m0 = rowBase + wr * 64 + mi * 16 + l4 * 4;
      const int n  = colBase + wc * 64 + ni * 16 + l15;
      if (z == 0) {
#pragma unroll
        for (int r = 0; r < 4; r++)
          Qb[(size_t)(m0 + r) * EMB + n] = (bf16_t)(acc[mi][ni][r] * QSCALE);
      } else if (z == 1) {
        // K fragment layout
#pragma unroll
        for (int r = 0; r < 4; r++) {
          int m = m0 + r;
          const int bq = m >> 11, s = m & 2047, hh = n >> 6, d = n & 63;
          size_t local = (size_t)(s >> 6) * 4096 + ((s >> 5) & 1) * 2048 +
                         (d >> 4) * 512 + ((d >> 3) & 1) * 256 + (s & 31) * 8 + (d & 7);
          Kf[(size_t)(bq * 16 + hh) * 131072 + local] = (bf16_t)acc[mi][ni][r];
        }
      } else {
        // V fragment layout: s0..s0+3 consecutive -> one 8B store
        const int bq = m0 >> 11, s0 = m0 & 2047, hh = n >> 6, d = n & 63;
        size_t local = (size_t)(s0 >> 6) * 4096 + ((s0 >> 4) & 3) * 1024 +
                       (d >> 5) * 512 + ((s0 >> 3) & 1) * 256 + (d & 31) * 8 + (s0 & 7);
        uint2 st;
        st.x = pkbf(acc[mi][ni][0], acc[mi][ni][1]);
        st.y = pkbf(acc[mi][ni][2], acc[mi][ni][3]);
        *reinterpret_cast<uint2*>(Vf + (size_t)(bq * 16 + hh) * 131072 + local) = st;
      }
    }
  }
}

// Output-projection GEMM: f32 C + residual.
__global__ void __launch_bounds__(256, 4)
gemm_out(const bf16_t* __restrict__ A, const bf16_t* __restrict__ Bw,
         float* __restrict__ Cf, const float* __restrict__ resid) {
  __shared__ bf16_t As[2][BM * BKT];
  __shared__ bf16_t Bs[2][BN * BKT];
  const int K = EMB, N = EMB;
  const int t    = threadIdx.x;
  const int lane = t & 63, w = t >> 6;
  const int wr = w >> 1, wc = w & 1;
  const int l15 = lane & 15, l4 = lane >> 4;

  const int lin = blockIdx.x + 8 * blockIdx.y;
  const int nl  = (lin & 7) * 64 + (lin >> 3);
  const int rowBase = (nl >> 3) * BM, colBase = (nl & 7) * BN;

  f32x4 acc[4][4];
#pragma unroll
  for (int i = 0; i < 4; i++)
#pragma unroll
    for (int j = 0; j < 4; j++) acc[i][j] = f32x4{0.f, 0.f, 0.f, 0.f};

  const int t16 = t * 16;

#pragma unroll
  for (int i = 0; i < 2; ++i) {
    int off  = i * 4096 + t16;
    int row  = off >> 6, colb = off & 63;
    gload_lds16((const char*)A  + (((size_t)(rowBase + row)) * K) * 2 + colb, (char*)As[0] + off);
    gload_lds16((const char*)Bw + (((size_t)(colBase + row)) * K) * 2 + colb, (char*)Bs[0] + off);
  }
  __syncthreads();

  int cur = 0;
  for (int k0 = 0; k0 < K; k0 += BKT) {
    if (k0 + BKT < K) {
      const int nb = cur ^ 1;
#pragma unroll
      for (int i = 0; i < 2; ++i) {
        int off  = i * 4096 + t16;
        int row  = off >> 6, colb = off & 63;
        gload_lds16((const char*)A  + (((size_t)(rowBase + row)) * K + k0 + BKT) * 2 + colb, (char*)As[nb] + off);
        gload_lds16((const char*)Bw + (((size_t)(colBase + row)) * K + k0 + BKT) * 2 + colb, (char*)Bs[nb] + off);
      }
    }
    {
      bf16x8 af[4], bfb[4];
#pragma unroll
      for (int mi = 0; mi < 4; mi++)
        af[mi] = *reinterpret_cast<const bf16x8*>(
            &As[cur][(wr * 64 + mi * 16 + l15) * BKT + l4 * 8]);
#pragma unroll
      for (int ni = 0; ni < 4; ni++)
        bfb[ni] = *reinterpret_cast<const bf16x8*>(
            &Bs[cur][(wc * 64 + ni * 16 + l15) * BKT + l4 * 8]);
      __builtin_amdgcn_s_setprio(1);
#pragma unroll
      for (int mi = 0; mi < 4; mi++)
#pragma unroll
        for (int ni = 0; ni < 4; ni++)
          acc[mi][ni] = __builtin_amdgcn_mfma_f32_16x16x32_bf16(
              af[mi], bfb[ni], acc[mi][ni], 0, 0, 0);
      __builtin_amdgcn_s_setprio(0);
    }
    __syncthreads();
    cur ^= 1;
  }

#pragma unroll
  for (int mi = 0; mi < 4; mi++) {
#pragma unroll
    for (int ni = 0; ni < 4; ni++) {
      const int m0 = rowBase + wr * 64 + mi * 16 + l4 * 4;
      const int n  = colBase + wc * 64 + ni * 16 + l15;
#pragma unroll
      for (int r = 0; r < 4; r++) {
        int m = m0 + r;
        Cf[(size_t)m * N + n] = acc[mi][ni][r] + resid[(size_t)m * N + n];
      }
    }
  }
}

// ---------------------------------------------------------------------------
// Flash attention — R10/R15 kernel VERBATIM (106.0-106.9 us: VGPR 56, no
// scratch, 0 bank conflicts). 512 thr = 8 waves x 32 q-rows; KVBLK=64;
// fragment-ordered K/V (LDS reads = base + frag*1024 + lane*16; staging =
// linear 8KB copies). Swapped-operand 32x32x16, POST-softmax masking, no
// online max (Q pre-scaled; P = exp2(acc)), VALU ps denominator.
// *** FROZEN — seven structural variants falsified: KVB=128/mask-hoist
// *** (R5-R8: scratch spills ~0.5GB r/w), occupancy/phase-diversity (R11:
// *** null), no-LDS (R12: latency-bound), T15 pipeline (R14: -16%),
// *** KV-split (R17: -9%, occupancy unchanged at 39% => not grid-bound).
// ---------------------------------------------------------------------------
__global__ void __launch_bounds__(512, 2)
attn32(const bf16_t* __restrict__ Qb, const bf16_t* __restrict__ Kh,
       const bf16_t* __restrict__ Vt, const uint16_t* __restrict__ Mand,
       bf16_t* __restrict__ ctx) {
  __shared__ __align__(16) bf16_t Ks[2][64 * 64];
  __shared__ __align__(16) bf16_t Vs[2][64 * 64];

  const int t = threadIdx.x, lane = t & 63, wid = t >> 6;
  const int q = lane & 31, hi = lane >> 5;
  const int l16 = lane * 16;

  // XCD swizzle: 512 blocks; mask/K/V sharers land on the same XCD
  const int lin = blockIdx.x + 8 * (blockIdx.y + 16 * blockIdx.z);
  const int nl  = (lin & 7) * 64 + (lin >> 3);
  const int bx = nl & 7, h = (nl >> 3) & 15, b = nl >> 7;

  const int q0 = bx * 256 + wid * 32;
  const int qrow = b * SEQ + q0 + q;

  const char* kg = (const char*)(Kh + ((size_t)(b * NB_HEAD + h)) * SEQ * DH);
  const char* vg = (const char*)(Vt + ((size_t)(b * NB_HEAD + h)) * SEQ * DH);

  const bf16_t* qp = Qb + (size_t)qrow * EMB + h * DH + hi * 8;
  bf16x8 qf[4];
#pragma unroll
  for (int d = 0; d < 4; d++) qf[d] = *reinterpret_cast<const bf16x8*>(qp + d * 16);

  f32x16 o0 = {0}, o1 = {0};
  float lrun = 0.f;
  const uint16_t* mbase = Mand + (size_t)qrow * SEQ;

  // prologue: stage tile 0 into buf 0 (linear 8KB copies)
  gload_lds16(kg + t * 16, (char*)Ks[0] + t * 16);
  gload_lds16(vg + t * 16, (char*)Vs[0] + t * 16);
  __syncthreads();

  int cur = 0;
  for (int kb = 0; kb < SEQ; kb += 64) {
    if (kb + 64 < SEQ) {
      const int nb = cur ^ 1;
      gload_lds16(kg + (size_t)(kb + 64) * 128 + t * 16, (char*)Ks[nb] + t * 16);
      gload_lds16(vg + (size_t)(kb + 64) * 128 + t * 16, (char*)Vs[nb] + t * 16);
    }

    const char* kls = (const char*)Ks[cur];
    f32x16 p0 = {0}, p1 = {0};
    __builtin_amdgcn_s_setprio(1);
#pragma unroll
    for (int dsl = 0; dsl < 4; dsl++) {
      bf16x8 kf0 = *reinterpret_cast<const bf16x8*>(kls + dsl * 1024 + l16);
      bf16x8 kf1 = *reinterpret_cast<const bf16x8*>(kls + 4096 + dsl * 1024 + l16);
      p0 = __builtin_amdgcn_mfma_f32_32x32x16_bf16(kf0, qf[dsl], p0, 0, 0, 0);
      p1 = __builtin_amdgcn_mfma_f32_32x32x16_bf16(kf1, qf[dsl], p1, 0, 0, 0);
    }
    __builtin_amdgcn_s_setprio(0);

    uint4 mv[4];
#pragma unroll
    for (int ks = 0; ks < 4; ks++)
      mv[ks] = *reinterpret_cast<const uint4*>(mbase + kb + 16 * ks + 8 * hi);

    float ps = 0.f;
#pragma unroll
    for (int i = 0; i < 16; i++) { p0[i] = __builtin_amdgcn_exp2f(p0[i]); ps += p0[i]; }
#pragma unroll
    for (int i = 0; i < 16; i++) { p1[i] = __builtin_amdgcn_exp2f(p1[i]); ps += p1[i]; }
    ps += __shfl_xor(ps, 32);
    lrun += ps;

    const char* vls = (const char*)Vs[cur];
#pragma unroll
    for (int ks = 0; ks < 4; ks++) {
      const int s8 = (ks & 1) * 8;
      float e0, e1, e2, e3, e4, e5, e6, e7;
      if (ks < 2) {
        e0 = p0[s8+0]; e1 = p0[s8+1]; e2 = p0[s8+2]; e3 = p0[s8+3];
        e4 = p0[s8+4]; e5 = p0[s8+5]; e6 = p0[s8+6]; e7 = p0[s8+7];
      } else {
        e0 = p1[s8+0]; e1 = p1[s8+1]; e2 = p1[s8+2]; e3 = p1[s8+3];
        e4 = p1[s8+4]; e5 = p1[s8+5]; e6 = p1[s8+6]; e7 = p1[s8+7];
      }
      uint32_t a0 = pkbf(e0, e1), a1 = pkbf(e2, e3);
      uint32_t a2 = pkbf(e4, e5), a3 = pkbf(e6, e7);
      uint2v s02 = __builtin_amdgcn_permlane32_swap(a0, a2, false, false);
      uint2v s13 = __builtin_amdgcn_permlane32_swap(a1, a3, false, false);
      uint4 fr;
      fr.x = s02[0]; fr.y = s13[0]; fr.z = s02[1]; fr.w = s13[1];
      fr.x &= mv[ks].x; fr.y &= mv[ks].y; fr.z &= mv[ks].z; fr.w &= mv[ks].w;
      bf16x8 pa = __builtin_bit_cast(bf16x8, fr);
      bf16x8 vf0 = *reinterpret_cast<const bf16x8*>(vls + ks * 2048 + l16);
      bf16x8 vf1 = *reinterpret_cast<const bf16x8*>(vls + ks * 2048 + 1024 + l16);
      __builtin_amdgcn_s_setprio(1);
      o0 = __builtin_amdgcn_mfma_f32_32x32x16_bf16(vf0, pa, o0, 0, 0, 0);
      o1 = __builtin_amdgcn_mfma_f32_32x32x16_bf16(vf1, pa, o1, 0, 0, 0);
      __builtin_amdgcn_s_setprio(0);
    }

    __syncthreads();
    cur ^= 1;
  }

  float inv = 1.0f / lrun;
  bf16_t* cp = ctx + (size_t)qrow * EMB + h * DH;
#pragma unroll
  for (int g = 0; g < 4; g++) {
    uint2 st;
    st.x = pkbf(o0[4*g+0] * inv, o0[4*g+1] * inv);
    st.y = pkbf(o0[4*g+2] * inv, o0[4*g+3] * inv);
    *reinterpret_cast<uint2*>(cp + 8 * g + 4 * hi) = st;
    st.x = pkbf(o1[4*g+0] * inv, o1[4*g+1] * inv);
    st.y = pkbf(o1[4*g+2] * inv, o1[4*g+3] * inv);
    *reinterpret_cast<uint2*>(cp + 32 + 8 * g + 4 * hi) = st;
  }
}

// ---------------------------------------------------------------------------
// launcher
// ---------------------------------------------------------------------------
extern "C" void kernel_launch(void* const* d_in, const int* in_sizes, int n_in,
                              void* d_out, int out_size, void* d_ws, size_t ws_size,
                              hipStream_t stream) {
  const float*   hq   = (const float*)d_in[0];
  const float*   hk   = (const float*)d_in[1];
  const float*   hv   = (const float*)d_in[2];
  const uint8_t* mask = (const uint8_t*)d_in[3];
  const float*   Wq   = (const float*)d_in[4];
  const float*   Wk   = (const float*)d_in[5];
  const float*   Wv   = (const float*)d_in[6];
  const float*   Wo   = (const float*)d_in[7];
  float* out = (float*)d_out;

  char* ws = (char*)d_ws;
  const size_t SZ_H = (size_t)NTOK * EMB * 2;        // 16 MiB
  const size_t SZ_W = (size_t)EMB * EMB * 2;         // 2 MiB
  bf16_t* hq_b = (bf16_t*)(ws + 0 * SZ_H);
  bf16_t* hk_b = (bf16_t*)(ws + 1 * SZ_H);
  bf16_t* hv_b = (bf16_t*)(ws + 2 * SZ_H);
  bf16_t* Qb   = (bf16_t*)(ws + 3 * SZ_H);
  bf16_t* Kf   = (bf16_t*)(ws + 4 * SZ_H);
  bf16_t* Vf   = (bf16_t*)(ws + 5 * SZ_H);
  bf16_t* ctx  = (bf16_t*)(ws + 6 * SZ_H);
  bf16_t* Wq_b = (bf16_t*)(ws + 7 * SZ_H + 0 * SZ_W);
  bf16_t* Wk_b = (bf16_t*)(ws + 7 * SZ_H + 1 * SZ_W);
  bf16_t* Wv_b = (bf16_t*)(ws + 7 * SZ_H + 2 * SZ_W);
  bf16_t* Wo_b = (bf16_t*)(ws + 7 * SZ_H + 3 * SZ_W);

  const size_t MAND_OFF = 7 * SZ_H + 4 * SZ_W;                 // 120 MiB
  const size_t MAND_SZ  = (size_t)BATCH * SEQ * SEQ * 2;       // 32 MiB
  const bool bigws = ws_size >= MAND_OFF + MAND_SZ;
  // fallback: Mand aliases hq_b/hk_b (dead after gemm_qkv3; mkand runs after)
  uint16_t* Mand = bigws ? (uint16_t*)(ws + MAND_OFF) : (uint16_t*)ws;

  prep<<<bigws ? 22528 : 14336, 256, 0, stream>>>(
      hq, hk, hv, Wq, Wk, Wv, Wo,
      hq_b, hk_b, hv_b, Wq_b, Wk_b, Wv_b, Wo_b, mask, Mand);

  // fused QKV: 1536 blocks (was 3 launches x 512 blocks)
  gemm_qkv3<<<dim3(8, 64, 3), 256, 0, stream>>>(hq_b, hk_b, hv_b,
                                                Wq_b, Wk_b, Wv_b, Qb, Kf, Vf);

  if (!bigws) mkand<<<8192, 256, 0, stream>>>(mask, Mand);

  attn32<<<dim3(SEQ / 256, NB_HEAD, BATCH), 512, 0, stream>>>(Qb, Kf, Vf, Mand, ctx);

  gemm_out<<<dim3(8, 64), 256, 0, stream>>>(ctx, Wo_b, out, hq);
}